// Round 9
// baseline (115.421 us; speedup 1.0000x reference)
//
#include <hip/hip_runtime.h>

// RGate: apply Rx(angle[i]) to every qubit of a 22-qubit statevector.
// Gate on amp-bit k pairs indices at stride 2^k and uses angle[21-k].
//
// Diagnostic-driven split (R5: input-reading pass = 47us @1.06TB/s with
// nothing busy; all in-place kernels fast; structure changes = flat):
//   K1: xr,xi -> out copy fused with gates {0,1}(float4 pairs) {2-7}(shfl).
//       Zero LDS/barriers, 2048 blocks = max MLP on the input read.
//       K1's duration isolates the input-read cost.
//   K2: in-place streaming, gates {8-11}(reg) {12}(shfl32). Zero LDS.
//   K3: bits 13-21, R3/R5 measured-fast tiled kernel verbatim (~16.6us).

constexpr int NTOT = 1 << 22;   // 2^22 amplitudes

__device__ __forceinline__ void rotg(float& ar, float& ai, float& br, float& bi,
                                     float c, float s) {
    // a' = c*a - i*s*b ; b' = c*b - i*s*a
    float t0 = ar, t1 = ai, t2 = br, t3 = bi;
    ar = fmaf(c, t0,  s * t3);
    ai = fmaf(c, t1, -s * t2);
    br = fmaf(c, t2,  s * t1);
    bi = fmaf(c, t3, -s * t0);
}

// NB butterfly gates for amp bits K0..K0+NB-1; amp bit (K0+b) lives at
// register-index bit (MSH+b). Angles wave-uniform. N = regs per thread.
template<int K0, int NB, int MSH, int N>
__device__ __forceinline__ void gatesM(float (&ar)[N], float (&ai)[N],
                                       const float* __restrict__ ang) {
    #pragma unroll
    for (int b = 0; b < NB; ++b) {
        const int m = 1 << (MSH + b);
        float c, s;
        sincosf(0.5f * ang[21 - (K0 + b)], &s, &c);
        #pragma unroll
        for (int j = 0; j < N; ++j)
            if (!(j & m)) rotg(ar[j], ai[j], ar[j | m], ai[j | m], c, s);
    }
}

// Cross-lane gate: partner = lane ^ XOR. Symmetric update valid on both sides:
// x_r' = c*x_r + s*p_i ; x_i' = c*x_i - s*p_r.
template<int XOR, int N>
__device__ __forceinline__ void shflgate(float (&ar)[N], float (&ai)[N],
                                         float c, float s) {
    #pragma unroll
    for (int j = 0; j < N; ++j) {
        float pr = __shfl_xor(ar[j], XOR, 64);
        float pi = __shfl_xor(ai[j], XOR, 64);
        ar[j] = fmaf(c, ar[j],  s * pi);
        ai[j] = fmaf(c, ai[j], -s * pr);
    }
}

// ---------------- K1: copy + gates 0..7 (pure streaming) -------------------
// 2048 blocks x 256 thr, 8 amps/thread (2 float4 per array).
// flat = bid*1024 + t*4 covers bits 0-20 with q -> bit 21.
// Gates: 0,1 = float4-internal pair bits (reg bits 0,1);
//        2-7 = flat bits 2-7 = t bits 0-5 = LANE bits -> shfl_xor 1..32.
// Per wave-instr: 64 lanes x 16 B = 1 KB contiguous on both read and write.
__global__ __launch_bounds__(256) void rgate_K1(const float* __restrict__ xr,
                                                const float* __restrict__ xi,
                                                const float* __restrict__ ang,
                                                float* __restrict__ out) {
    const int t = threadIdx.x;
    const int flat = (blockIdx.x << 10) | (t << 2);

    float ar[8], ai[8];
    #pragma unroll
    for (int q = 0; q < 2; ++q) {
        const int i = flat | (q << 21);
        float4 vr = *(const float4*)(xr + i);
        float4 vi = *(const float4*)(xi + i);
        ar[4*q+0] = vr.x; ar[4*q+1] = vr.y; ar[4*q+2] = vr.z; ar[4*q+3] = vr.w;
        ai[4*q+0] = vi.x; ai[4*q+1] = vi.y; ai[4*q+2] = vi.z; ai[4*q+3] = vi.w;
    }

    gatesM<0, 2, 0>(ar, ai, ang);        // amp bits 0,1 (reg bits 0,1)
    {   // amp bits 2-7 = lane bits 0-5
        float c, s;
        sincosf(0.5f * ang[21 - 2], &s, &c); shflgate< 1>(ar, ai, c, s);
        sincosf(0.5f * ang[21 - 3], &s, &c); shflgate< 2>(ar, ai, c, s);
        sincosf(0.5f * ang[21 - 4], &s, &c); shflgate< 4>(ar, ai, c, s);
        sincosf(0.5f * ang[21 - 5], &s, &c); shflgate< 8>(ar, ai, c, s);
        sincosf(0.5f * ang[21 - 6], &s, &c); shflgate<16>(ar, ai, c, s);
        sincosf(0.5f * ang[21 - 7], &s, &c); shflgate<32>(ar, ai, c, s);
    }

    #pragma unroll
    for (int q = 0; q < 2; ++q) {
        const int i = flat | (q << 21);
        *(float4*)(out + i)        = make_float4(ar[4*q], ar[4*q+1], ar[4*q+2], ar[4*q+3]);
        *(float4*)(out + NTOT + i) = make_float4(ai[4*q], ai[4*q+1], ai[4*q+2], ai[4*q+3]);
    }
}

// ---------------- K2: gates 8..12, in-place streaming ----------------------
// 1024 blocks x 256 thr, 16 amps/thread. Zero LDS/barriers.
// base bits: 0-4 = t&31 (128 B contig), 5-6 = t>>6, 7 = b&1, 12 = lane bit 5,
// 13-21 = b>>1. reg j -> amp bits 8-11 (16 loads at stride 2^8).
// Per instr: lanes 0-31 and 32-63 each cover one full 128 B line.
__global__ __launch_bounds__(256) void rgate_K2(const float* __restrict__ ang,
                                                float* __restrict__ out) {
    const int t = threadIdx.x, b = blockIdx.x;
    const int base = (t & 31) | (((t >> 5) & 1) << 12) | ((t >> 6) << 5)
                   | ((b & 1) << 7) | ((b >> 1) << 13);
    float* outr = out;
    float* outi = out + NTOT;

    float ar[16], ai[16];
    #pragma unroll
    for (int j = 0; j < 16; ++j) ar[j] = outr[base + (j << 8)];
    #pragma unroll
    for (int j = 0; j < 16; ++j) ai[j] = outi[base + (j << 8)];

    gatesM<8, 4, 0>(ar, ai, ang);        // amp bits 8-11 (reg bits 0-3)
    {   // amp bit 12 = lane bit 5
        float c, s;
        sincosf(0.5f * ang[21 - 12], &s, &c);
        shflgate<32>(ar, ai, c, s);
    }

    #pragma unroll
    for (int j = 0; j < 16; ++j) outr[base + (j << 8)] = ar[j];
    #pragma unroll
    for (int j = 0; j < 16; ++j) outi[base + (j << 8)] = ai[j];
}

// ---------------- K3: bits 13..21 (h stride 8192) --------------------------
// VERBATIM from the measured-fast R3/R5 build (~16.6 us inferred).
// amp = h*8192 + l, h in [0,512); tile = all h x 16 contiguous l = 64 KB.
// 512 threads, 16 amps/thread. sub = t&15, hw = t>>4 in [0,32).
//  B1 (load):  h = j | (hw<<4) -> reg = h bits 0..3 -> gates 13-16;
//              then gate 17 (h bit 4 = lane bit 4) via __shfl_xor(.,16)
//  B2 (store): h = hw | (j<<5) -> reg = h bits 5..8 -> gates 18-21
// LDS sv[h*16+sub]: both arrangements conflict-free. XCD-contiguous remap.
__global__ __launch_bounds__(512, 4) void rgate_K3(const float* __restrict__ ang,
                                                   float* __restrict__ out) {
    __shared__ float2 sv[8192];          // 64 KB
    const int t   = threadIdx.x;
    const int bid = blockIdx.x;
    const int blk = (bid >> 3) | ((bid & 7) << 6);   // XCD-contiguous remap
    const int sub = t & 15, hw = t >> 4;
    const int lbase = (blk << 4) + sub;
    float* outr = out;
    float* outi = out + NTOT;

    float ar[16], ai[16];
    #pragma unroll
    for (int j = 0; j < 16; ++j) {
        const int g = ((j | (hw << 4)) << 13) + lbase;
        ar[j] = outr[g]; ai[j] = outi[g];
    }
    gatesM<13, 4, 0>(ar, ai, ang);       // gates 13-16

    {   // gate 17: partner = lane^16 (same wave)
        float c, s;
        sincosf(0.5f * ang[21 - 17], &s, &c);
        shflgate<16>(ar, ai, c, s);
    }

    #pragma unroll
    for (int j = 0; j < 16; ++j)
        sv[((j | (hw << 4)) << 4) + sub] = make_float2(ar[j], ai[j]);
    __syncthreads();

    #pragma unroll
    for (int j = 0; j < 16; ++j) {
        float2 v = sv[((hw | (j << 5)) << 4) + sub];
        ar[j] = v.x; ai[j] = v.y;
    }
    gatesM<18, 4, 0>(ar, ai, ang);       // gates 18-21

    #pragma unroll
    for (int j = 0; j < 16; ++j) {
        const int g = ((hw | (j << 5)) << 13) + lbase;
        outr[g] = ar[j]; outi[g] = ai[j];
    }
}

extern "C" void kernel_launch(void* const* d_in, const int* in_sizes, int n_in,
                              void* d_out, int out_size, void* d_ws, size_t ws_size,
                              hipStream_t stream) {
    const float* xr  = (const float*)d_in[0];
    const float* xi  = (const float*)d_in[1];
    const float* ang = (const float*)d_in[2];
    float* out = (float*)d_out;

    // K1: input read isolated: copy + gates 0-7 (fully overwrites d_out)
    rgate_K1<<<2048, 256, 0, stream>>>(xr, xi, ang, out);
    // K2: gates 8-12, in-place streaming
    rgate_K2<<<1024, 256, 0, stream>>>(ang, out);
    // K3: gates 13-21, in-place tiled (measured-fast)
    rgate_K3<<<512, 512, 0, stream>>>(ang, out);
}

// Round 10
// 105.909 us; speedup vs baseline: 1.0898x; 1.0898x over previous
//
#include <hip/hip_runtime.h>

// RGate: apply Rx(angle[i]) to every qubit of a 22-qubit statevector.
// Gate on amp-bit k pairs indices at stride 2^k and uses angle[21-k].
//
// Session diagnosis (R5/R9): the harness's 268 MB poison fill precedes our
// kernels; its LLC drain throttles the FIRST kernel's cold input reads to
// ~1 TB/s (~40-47 us regardless of structure: tiled=47, pure-stream=40).
// Kernels reading LLC-warm 'out' run 12-17 us. Passes are position-taxed,
// not structure-taxed. => Run the strided pass FIRST (pays the fixed tax),
// the 3-retile contiguous pass SECOND on warm data.
//   P1: bits 13-21, tile 512H x 16l, 1 retile + shfl for bit 17; xr,xi -> out.
//   P2: bits 0-12, contiguous 8192-amp tile, 3 retiles; in-place on out.
// Both kernel bodies are the R3/R5 measured-fast structures verbatim.

constexpr int NTOT = 1 << 22;   // 2^22 amplitudes

__device__ __forceinline__ void rotg(float& ar, float& ai, float& br, float& bi,
                                     float c, float s) {
    // a' = c*a - i*s*b ; b' = c*b - i*s*a
    float t0 = ar, t1 = ai, t2 = br, t3 = bi;
    ar = fmaf(c, t0,  s * t3);
    ai = fmaf(c, t1, -s * t2);
    br = fmaf(c, t2,  s * t1);
    bi = fmaf(c, t3, -s * t0);
}

// NB butterfly gates for amp bits K0..K0+NB-1; amp bit (K0+b) lives at
// register-index bit (MSH+b). Angles wave-uniform.
template<int K0, int NB, int MSH>
__device__ __forceinline__ void gatesM(float (&ar)[16], float (&ai)[16],
                                       const float* __restrict__ ang) {
    #pragma unroll
    for (int b = 0; b < NB; ++b) {
        const int m = 1 << (MSH + b);
        float c, s;
        sincosf(0.5f * ang[21 - (K0 + b)], &s, &c);
        #pragma unroll
        for (int j = 0; j < 16; ++j)
            if (!(j & m)) rotg(ar[j], ai[j], ar[j | m], ai[j | m], c, s);
    }
}

// Cross-lane gate: partner = lane ^ XOR. Symmetric update valid on both sides:
// x_r' = c*x_r + s*p_i ; x_i' = c*x_i - s*p_r.
template<int XOR>
__device__ __forceinline__ void shflgate(float (&ar)[16], float (&ai)[16],
                                         float c, float s) {
    #pragma unroll
    for (int j = 0; j < 16; ++j) {
        float pr = __shfl_xor(ar[j], XOR, 64);
        float pi = __shfl_xor(ai[j], XOR, 64);
        ar[j] = fmaf(c, ar[j],  s * pi);
        ai[j] = fmaf(c, ai[j], -s * pr);
    }
}

// P2 LDS swizzle: fold index bits 4..7 into bank-pair bits 0..3.
// Self-inverse bijection on [0,8192). Verified b64 floor for all
// four arrangements (lane strides 4, 1-contig, 64-contig, 4).
__device__ __forceinline__ int slotA(int i) { return i ^ ((i >> 4) & 15); }

// ---------------- P1: bits 13..21 (h stride 8192), reads inputs ------------
// amp = h*8192 + l, h in [0,512); tile = all h x 16 contiguous l = 64 KB.
// 512 threads, 16 amps/thread. sub = t&15, hw = t>>4 in [0,32).
//  load:  h = j | (hw<<4) -> reg = h bits 0..3 -> gates 13-16;
//         then gate 17 (h bit 4 = lane bit 4) via __shfl_xor(.,16)
//  store: h = hw | (j<<5) -> reg = h bits 5..8 -> gates 18-21
// LDS sv[h*16+sub]: both arrangements conflict-free. XCD-contiguous remap.
__global__ __launch_bounds__(512, 4) void rgate_P1(const float* __restrict__ xr,
                                                   const float* __restrict__ xi,
                                                   const float* __restrict__ ang,
                                                   float* __restrict__ out) {
    __shared__ float2 sv[8192];          // 64 KB
    const int t   = threadIdx.x;
    const int bid = blockIdx.x;
    const int blk = (bid >> 3) | ((bid & 7) << 6);   // XCD-contiguous remap
    const int sub = t & 15, hw = t >> 4;
    const int lbase = (blk << 4) + sub;
    float* outr = out;
    float* outi = out + NTOT;

    float ar[16], ai[16];
    #pragma unroll
    for (int j = 0; j < 16; ++j) {
        const int g = ((j | (hw << 4)) << 13) + lbase;
        ar[j] = xr[g]; ai[j] = xi[g];
    }
    gatesM<13, 4, 0>(ar, ai, ang);       // gates 13-16

    {   // gate 17: partner = lane^16 (same wave)
        float c, s;
        sincosf(0.5f * ang[21 - 17], &s, &c);
        shflgate<16>(ar, ai, c, s);
    }

    #pragma unroll
    for (int j = 0; j < 16; ++j)
        sv[((j | (hw << 4)) << 4) + sub] = make_float2(ar[j], ai[j]);
    __syncthreads();

    #pragma unroll
    for (int j = 0; j < 16; ++j) {
        float2 v = sv[((hw | (j << 5)) << 4) + sub];
        ar[j] = v.x; ai[j] = v.y;
    }
    gatesM<18, 4, 0>(ar, ai, ang);       // gates 18-21

    #pragma unroll
    for (int j = 0; j < 16; ++j) {
        const int g = ((hw | (j << 5)) << 13) + lbase;
        outr[g] = ar[j]; outi[g] = ai[j];
    }
}

// ---------------- P2: bits 0..12, tile = 8192 contiguous, in-place ---------
// 512 threads, 16 amps/thread, LDS 8192 float2 = 64 KB (2 blocks/CU).
// Arrangements (tile-local index i, reg j):
//  A1 (load):  i = (t<<2) + r + (q<<11), j=r+4q -> reg bits {0,1,11,12};
//              gates 11,12 (float4 loads)
//  A2:         i = (t&3)  + (j<<2) + ((t>>2)<<6)  -> bits {2..5};  gates 2-5
//  A3:         i = (t&63) + (j<<6) + ((t>>6)<<10) -> bits {6..9};  gates 6-9
//  A4 (store): i = r + ((t&255)<<2) + (q<<10) + ((t>>8)<<12)
//              -> reg bits {0,1,10,11}; gates 0,1,10 (float4 stores)
// Reads and writes the same exclusive tile of 'out' (LLC-warm from P1).
__global__ __launch_bounds__(512, 4) void rgate_P2(const float* __restrict__ ang,
                                                   float* __restrict__ out) {
    __shared__ float2 sv[8192];          // 64 KB
    const int t  = threadIdx.x;
    const int g0 = blockIdx.x << 13;
    float* outr = out;
    float* outi = out + NTOT;

    float ar[16], ai[16];
    #pragma unroll
    for (int q = 0; q < 4; ++q) {
        const int i = (t << 2) + (q << 11);
        float4 vr = *(const float4*)(outr + g0 + i);
        float4 vi = *(const float4*)(outi + g0 + i);
        ar[4*q+0] = vr.x; ar[4*q+1] = vr.y; ar[4*q+2] = vr.z; ar[4*q+3] = vr.w;
        ai[4*q+0] = vi.x; ai[4*q+1] = vi.y; ai[4*q+2] = vi.z; ai[4*q+3] = vi.w;
    }
    gatesM<11, 2, 2>(ar, ai, ang);       // gates 11,12 on reg bits 2,3 (=q)

    #pragma unroll
    for (int q = 0; q < 4; ++q)
        #pragma unroll
        for (int r = 0; r < 4; ++r)
            sv[slotA((t << 2) + r + (q << 11))] = make_float2(ar[4*q+r], ai[4*q+r]);
    __syncthreads();

    // A2: reg bits {2..5}
    const int b2 = (t & 3) + ((t >> 2) << 6);
    #pragma unroll
    for (int j = 0; j < 16; ++j) {
        float2 v = sv[slotA(b2 + (j << 2))];
        ar[j] = v.x; ai[j] = v.y;
    }
    gatesM<2, 4, 0>(ar, ai, ang);
    #pragma unroll
    for (int j = 0; j < 16; ++j)
        sv[slotA(b2 + (j << 2))] = make_float2(ar[j], ai[j]);
    __syncthreads();

    // A3: reg bits {6..9}
    const int b3 = (t & 63) + ((t >> 6) << 10);
    #pragma unroll
    for (int j = 0; j < 16; ++j) {
        float2 v = sv[slotA(b3 + (j << 6))];
        ar[j] = v.x; ai[j] = v.y;
    }
    gatesM<6, 4, 0>(ar, ai, ang);
    #pragma unroll
    for (int j = 0; j < 16; ++j)
        sv[slotA(b3 + (j << 6))] = make_float2(ar[j], ai[j]);
    __syncthreads();

    // A4: reg bits {0,1,10,11} -> gates 0,1 (reg bits 0,1) + gate 10 (reg bit 2)
    const int b4 = ((t & 255) << 2) + ((t >> 8) << 12);
    #pragma unroll
    for (int q = 0; q < 4; ++q)
        #pragma unroll
        for (int r = 0; r < 4; ++r) {
            float2 v = sv[slotA(b4 + r + (q << 10))];
            ar[4*q+r] = v.x; ai[4*q+r] = v.y;
        }
    gatesM<0, 2, 0>(ar, ai, ang);        // gates 0,1
    gatesM<10, 1, 2>(ar, ai, ang);       // gate 10 on reg bit 2 (=q)

    #pragma unroll
    for (int q = 0; q < 4; ++q) {
        const int i = b4 + (q << 10);
        *(float4*)(outr + g0 + i) = make_float4(ar[4*q], ar[4*q+1], ar[4*q+2], ar[4*q+3]);
        *(float4*)(outi + g0 + i) = make_float4(ai[4*q], ai[4*q+1], ai[4*q+2], ai[4*q+3]);
    }
}

extern "C" void kernel_launch(void* const* d_in, const int* in_sizes, int n_in,
                              void* d_out, int out_size, void* d_ws, size_t ws_size,
                              hipStream_t stream) {
    const float* xr  = (const float*)d_in[0];
    const float* xi  = (const float*)d_in[1];
    const float* ang = (const float*)d_in[2];
    float* out = (float*)d_out;

    // P1: bits 13-21, xr/xi -> out (cold reads pay the fixed position tax;
    //     fully overwrites d_out)
    rgate_P1<<<512, 512, 0, stream>>>(xr, xi, ang, out);
    // P2: bits 0-12, in-place on LLC-warm out
    rgate_P2<<<512, 512, 0, stream>>>(ang, out);
}